// Round 1
// baseline (435.641 us; speedup 1.0000x reference)
//
#include <hip/hip_runtime.h>
#include <math.h>

// Problem constants (fixed by the reference file)
#define BATCH 16
#define CHAN  64
#define Hh    256
#define Ww    256
#define HP    128   // pooled H
#define WP    128   // pooled W
#define TH    32    // output tile rows per block
#define TW    32    // output tile cols per block
#define CH    (TH + 2)  // canvas rows (halo 1)
#define CW    (TW + 2)  // canvas cols
#define CS    36        // padded LDS row stride (avoid pow2 strides)

// One block = one 32x32 output tile of one (b,c) image.
// Stage 1: scatter pooled values into an LDS canvas with last-write-wins
//          duplicate resolution (winner = max flat pooled index, matching
//          numpy/XLA sequential scatter semantics).
// Stage 2: 3x3 windowed max over the canvas; out-of-image cells are -inf
//          (reduce_window 'same' padding), unwritten in-image cells are 0.
__global__ __launch_bounds__(256) void unpool_dilate_kernel(
    const float* __restrict__ f, const int* __restrict__ prov,
    float* __restrict__ out)
{
    __shared__ int   s_key[CH * CS];
    __shared__ float s_val[CH * CS];

    const int tid = threadIdx.x;
    const int bc  = blockIdx.y;            // 0..1023  (b*C + c)
    const int ty  = blockIdx.x >> 3;       // Ww/TW = 8 tiles per image row
    const int tx  = blockIdx.x & 7;
    const int y0  = ty * TH;
    const int x0  = tx * TW;

    // ---- init canvas: key=0 (empty), val=0 in-image / -inf out-of-image ----
    for (int idx = tid; idx < CH * CW; idx += 256) {
        const int lr = idx / CW, lc = idx - lr * CW;
        const int r = y0 - 1 + lr, c = x0 - 1 + lc;
        s_key[lr * CS + lc] = 0;
        s_val[lr * CS + lc] =
            (r >= 0 && r < Hh && c >= 0 && c < Ww) ? 0.0f : -INFINITY;
    }

    // ---- pooled-cell candidate region for this canvas ----
    // pooled cell (pi,pj) targets rows clip(2*pi+dy) in {2pi..2pi+2}
    const int pi_min = (y0 == 0) ? 0 : (y0 / 2 - 1);
    const int pj_min = (x0 == 0) ? 0 : (x0 / 2 - 1);
    const int pi_max = min(HP - 1, y0 / 2 + TH / 2);
    const int pj_max = min(WP - 1, x0 / 2 + TW / 2);
    const int npi = pi_max - pi_min + 1;     // <= 18
    const int npj = pj_max - pj_min + 1;     // <= 18
    const int ncell = npi * npj;             // <= 324 -> <= 2 per thread

    const size_t in_base = (size_t)bc * (HP * WP);

    int   m_q[2];
    int   m_li[2];
    float m_f[2];
    int   nmine = 0;

    __syncthreads();

    // ---- pass 1: claim cells via atomicMax on key = flat pooled idx + 1 ----
    for (int k = tid; k < ncell; k += 256) {
        const int ki = k / npj;
        const int pi = pi_min + ki;
        const int pj = pj_min + (k - ki * npj);
        const int q  = pi * WP + pj;
        const int p  = prov[in_base + q];
        const int r  = p >> 8;               // Ww == 256
        const int c  = p & 255;
        const int lr = r - (y0 - 1);
        const int lc = c - (x0 - 1);
        if (lr >= 0 && lr < CH && lc >= 0 && lc < CW) {
            const int li = lr * CS + lc;
            atomicMax(&s_key[li], q + 1);
            m_q[nmine]  = q;
            m_li[nmine] = li;
            m_f[nmine]  = f[in_base + q];    // prefetch value
            nmine++;
        }
    }
    __syncthreads();

    // ---- pass 2: winners write their value (conflict-free) ----
    for (int t = 0; t < nmine; ++t) {
        if (s_key[m_li[t]] == m_q[t] + 1) s_val[m_li[t]] = m_f[t];
    }
    __syncthreads();

    // ---- stage 2: 3x3 max, 4 outputs per thread, float4 store ----
    const int orow = tid >> 3;               // 0..31
    const int oc0  = (tid & 7) * 4;          // 0,4,...,28
    float4 res;
    float* rp = &res.x;
    #pragma unroll
    for (int j = 0; j < 4; ++j) {
        const int lc = oc0 + j;              // canvas cols lc..lc+2
        float m = -INFINITY;
        #pragma unroll
        for (int dr = 0; dr < 3; ++dr) {
            const float* row = &s_val[(orow + dr) * CS + lc];
            m = fmaxf(m, fmaxf(fmaxf(row[0], row[1]), row[2]));
        }
        rp[j] = m;
    }
    const size_t obase = (size_t)bc * (Hh * Ww)
                       + (size_t)(y0 + orow) * Ww + (x0 + oc0);
    *(float4*)(out + obase) = res;
}

extern "C" void kernel_launch(void* const* d_in, const int* in_sizes, int n_in,
                              void* d_out, int out_size, void* d_ws, size_t ws_size,
                              hipStream_t stream) {
    const float* f    = (const float*)d_in[0];
    const int*   prov = (const int*)d_in[1];
    // d_in[2]=h, d_in[3]=w are fixed at 256 by the reference; hardcoded.
    float* out = (float*)d_out;

    dim3 grid((Hh / TH) * (Ww / TW), BATCH * CHAN);  // (64, 1024)
    unpool_dilate_kernel<<<grid, 256, 0, stream>>>(f, prov, out);
}